// Round 7
// baseline (196.065 us; speedup 1.0000x reference)
//
#include <hip/hip_runtime.h>
#include <hip/hip_fp16.h>
#include <math.h>

#define NPROJ 96
#define NANG  96
#define DET   192
#define NPIX  16384            // 128*128
#define SLICE (NANG*DET)       // 18432

// wq stores quad rows [16,112) only (reads touch rows 19..111)
#define WQROW0   16
#define WQROWS   96
#define WQSLICEB (WQROWS*128*16)   // 196608 bytes per projection

// DSD/DU = DSD/DV = 1000/3.5
#define KPROJ 285.7142857142857f

__device__ __forceinline__ float frcp(float x) { return __builtin_amdgcn_rcpf(x); }

__device__ __forceinline__ float ffract(float x) {
#if __has_builtin(__builtin_amdgcn_fractf)
    return __builtin_amdgcn_fractf(x);
#else
    return x - floorf(x);
#endif
}

typedef __fp16 h2 __attribute__((ext_vector_type(2)));

__device__ __forceinline__ unsigned pack2(float a, float b) {
    h2 p = __builtin_amdgcn_cvt_pkrtz(a, b);
    return __builtin_bit_cast(unsigned, p);
}
__device__ __forceinline__ h2 as_h2(unsigned u) { return __builtin_bit_cast(h2, u); }

#if __has_builtin(__builtin_amdgcn_fdot2)
#define FDOT2(a, b, c) __builtin_amdgcn_fdot2((a), (b), (c), false)
#else
__device__ __forceinline__ float FDOT2(h2 a, h2 b, float c) {
    return c + (float)a[0] * (float)b[0] + (float)a[1] * (float)b[1];
}
#endif

// ---------------------------------------------------------------------------
// K1: deriv = grad_lastdim(sino * weight) -> DIFFERENCE pairs:
// derivp[row][d] = half2(g[d], g[d+1]-g[d])  =>  lerp weight is (1, f).
// ---------------------------------------------------------------------------
__global__ __launch_bounds__(192) void k_deriv(const float* __restrict__ sino,
                                               const float* __restrict__ wgt,
                                               unsigned* __restrict__ derivp) {
    __shared__ float row[DET];
    const int r = blockIdx.x;          // p*96 + a
    const int d = threadIdx.x;         // 0..191
    const int base = r * DET + d;
    row[d] = sino[base] * wgt[base];
    __syncthreads();
    auto grad = [&](int i) -> float {
        i = (i > DET-1) ? DET-1 : i;
        if (i == 0)       return row[1] - row[0];
        if (i == DET-1)   return row[DET-1] - row[DET-2];
        return 0.5f * (row[i+1] - row[i-1]);
    };
    const float g0 = grad(d), g1 = grad(d+1);
    derivp[base] = pack2(g0, g1 - g0);
}

// ---------------------------------------------------------------------------
// K2: 2D backprojection + cosine weighting — LDS-staged rows.
// Theory (r7): the old per-px GLOBAL gathers hit a 768B row -> each wave-load
// serializes over ~12 cachelines in L1 (line replay) -> ~50us hidden cost.
// Now: the current angle's 192-entry diff-pair row lives in LDS
// (double-buffered; prefetch angle a+2 issued BEFORE compute of angle a;
// ONE barrier per angle). ds_read_b32 per px-angle: lane stride
// |d(i0)/dx| = |cos| <= 1 -> consecutive-or-broadcast, ~conflict-free.
// 4 px/thread, grid (96 p, 16 chunks) = 1536 blocks = 6/CU = 24 waves/CU.
// Math, diff-pair weights, quad + table epilogue identical to r6.
// ---------------------------------------------------------------------------
__global__ __launch_bounds__(256) void k_bp2d_l(const unsigned* __restrict__ derivp,
                                                unsigned* __restrict__ wq_dw,
                                                uint2* __restrict__ tbl) {
    __shared__ float sc[NANG], ss[NANG];
    __shared__ unsigned dp[2][DET];    // double-buffered angle row (1.5 KB)
    __shared__ float buf[1024];
    const int p   = blockIdx.x;
    const int tid = threadIdx.x;

    if (tid < NANG) {
        float s_, c_;
        sincosf((float)tid * (float)(3.14159265358979323846 / 96.0), &s_, &c_);
        sc[tid] = c_; ss[tid] = s_;
    }

    // K3 cone-beam geometry trig for this projection (uniform over block)
    float sb2, cb2;
    sincosf((float)p * (float)(2.0 * 3.14159265358979323846 / 96.0), &sb2, &cb2);

    const int pixbase = blockIdx.y * 1024;
    float acc[4], fx[4], fy[4];
    #pragma unroll
    for (int i = 0; i < 4; ++i) {
        const int pix = pixbase + i*256 + tid;
        fx[i] = (float)(pix & 127) - 63.5f;
        fy[i] = (float)(pix >> 7)  - 63.5f;
        acc[i] = 0.0f;
    }

    const unsigned* rowp = derivp + p * SLICE;
    unsigned rcur = 0;
    if (tid < DET) {
        dp[0][tid] = rowp[tid];                  // angle 0 row
        rcur       = rowp[DET + tid];            // angle 1 prefetched
    }
    __syncthreads();   // trig + dp[0] ready

    for (int a = 0; a < NANG; ++a) {
        unsigned rnext = 0;
        const int anext = (a + 2 < NANG) ? (a + 2) : (NANG - 1);
        if (tid < DET) rnext = rowp[anext * DET + tid];   // issue early (T14)

        const float cb = sc[a], sb = ss[a];
        const unsigned* row = dp[a & 1];
        #pragma unroll
        for (int i = 0; i < 4; ++i) {
            const float pos = fmaf(cb, fx[i], fmaf(sb, fy[i], 95.5f));
            const int   i0  = (int)pos;            // pos in [5,186]
            const float f   = ffract(pos);
            acc[i] = FDOT2(as_h2(row[i0]), as_h2(pack2(1.0f, f)), acc[i]);
        }

        if (tid < DET) { dp[(a + 1) & 1][tid] = rcur; rcur = rnext; }
        __syncthreads();   // writes of dp[(a+1)&1] visible; reads of dp[a&1] done
    }

    #pragma unroll
    for (int i = 0; i < 4; ++i) {
        const float w = 1000.0f * rsqrtf(1000000.0f + fx[i]*fx[i] + fy[i]*fy[i]);
        buf[i*256 + tid] = acc[i] * w;
    }
    __syncthreads();

    unsigned* sq = wq_dw + p * (WQROWS * 128 * 4);
    uint2*    tp = tbl   + p * NPIX;
    #pragma unroll
    for (int i = 0; i < 4; ++i) {
        const int l   = i*256 + tid;
        const int pix = pixbase + l;
        const int u   = pix & 127;
        const int v   = pix >> 7;
        const float v0 = buf[l];
        const float v1 = (u < 127) ? buf[l + 1] : 0.0f;   // u=127 pair unused
        const unsigned pr = pack2(v0, v1 - v0);
        #pragma unroll
        for (int k = 0; k < 4; ++k) {
            const int vb = v - k;
            if (vb >= WQROW0 && vb < WQROW0 + WQROWS)
                sq[(((vb - WQROW0) << 7) + u) << 2 | k] = pr;
        }
        // K3 prologue table entry for (p, pix)
        const float t3   = fmaf(fx[i], cb2,  fy[i] * sb2);
        const float sd3  = fmaf(fy[i], cb2, -fx[i] * sb2);
        const float invr = frcp(500.0f + t3);
        const float pu   = fmaf(KPROJ * sd3, invr, 63.5f);
        const int   iu0  = (int)pu;              // [11,116]
        const float fu   = ffract(pu);
        float w2 = 1000.0f * invr; w2 *= w2;
        const float Kz   = KPROJ * invr;         // > 0
        const unsigned kzi = (__builtin_bit_cast(unsigned, Kz) & ~127u) | (unsigned)iu0;
        uint2 e; e.x = pack2(w2, fu * w2); e.y = kzi;
        tp[pix] = e;                             // coalesced dwordx2
    }
}

// ---------------------------------------------------------------------------
// K3: 3D cone-beam backprojection + PReLU — r6 version verbatim (93.0 us,
// VALUBusy 76%): quad-z4 MATH + per-(beta,pixel) prologue table from K2.
// grid (64 y-pairs, 32 z-chunks) = 2048 blocks = 32 waves/CU. No LDS, no
// barriers, no trig. pu in [11,116], pv in [19,108] -> no masks.
// NOTE: the b=95 table prefetch reads one slice past tbl — lands in the
// derivp region of the same workspace allocation (valid memory, unused).
// ---------------------------------------------------------------------------
__global__ __launch_bounds__(256, 8) void k_bp3d_t(const unsigned char* __restrict__ wq,
                                                   const uint2* __restrict__ tbl,
                                                   const float* __restrict__ prelu,
                                                   float* __restrict__ out) {
    const int tid = threadIdx.x;
    const int x   = tid & 127;
    const int y   = (blockIdx.x << 1) | (tid >> 7);
    const int z0  = blockIdx.y << 2;
    const int pix = (y << 7) + x;

    const float zlo = (float)z0 - 63.5f;

    float acc[4];
    #pragma unroll
    for (int j = 0; j < 4; ++j) acc[j] = 0.0f;

    const uint2* tp = tbl + pix;
    const unsigned char* sp = wq;

    uint2 Tc = *tp; tp += NPIX;

    for (int b = 0; b < NPROJ; ++b, tp += NPIX, sp += WQSLICEB) {
        const uint2 Tn = *tp;                    // next-beta prefetch
        const h2    wuw = as_h2(Tc.x);
        const int   iu0 = (int)(Tc.y & 127u);
        const float Kz  = __builtin_bit_cast(float, Tc.y & ~127u);
        const int   ub2 = (iu0 << 4) - (WQROW0 << 11);   // fold row-trim offset

        // z-pair 0 (z0, z0+1)
        const float pvA0 = fmaf(Kz, zlo, 63.5f);
        const float pvB0 = pvA0 + Kz;
        const int   ivA0 = (int)pvA0;            // [19,108]
        const int   d0   = (int)pvB0 - ivA0;     // 0 or 1
        const float fvA0 = ffract(pvA0);
        const float fvB0 = ffract(pvB0);
        const uint4 q0   = *(const uint4*)(sp + ((ivA0 << 11) + ub2));

        // z-pair 1 (z0+2, z0+3)
        const float pvA1 = fmaf(Kz, zlo + 2.0f, 63.5f);
        const float pvB1 = pvA1 + Kz;
        const int   ivA1 = (int)pvA1;
        const int   d1   = (int)pvB1 - ivA1;
        const float fvA1 = ffract(pvA1);
        const float fvB1 = ffract(pvB1);
        const uint4 q1   = *(const uint4*)(sp + ((ivA1 << 11) + ub2));

        {
            const float tA = FDOT2(as_h2(q0.x), wuw, 0.0f);
            const float bA = FDOT2(as_h2(q0.y), wuw, 0.0f);
            acc[0] += fmaf(fvA0, bA - tA, tA);
            const unsigned tBv = d0 ? q0.y : q0.x;
            const unsigned bBv = d0 ? q0.z : q0.y;
            const float tB = FDOT2(as_h2(tBv), wuw, 0.0f);
            const float bB = FDOT2(as_h2(bBv), wuw, 0.0f);
            acc[1] += fmaf(fvB0, bB - tB, tB);
        }
        {
            const float tA = FDOT2(as_h2(q1.x), wuw, 0.0f);
            const float bA = FDOT2(as_h2(q1.y), wuw, 0.0f);
            acc[2] += fmaf(fvA1, bA - tA, tA);
            const unsigned tBv = d1 ? q1.y : q1.x;
            const unsigned bBv = d1 ? q1.z : q1.y;
            const float tB = FDOT2(as_h2(tBv), wuw, 0.0f);
            const float bB = FDOT2(as_h2(bBv), wuw, 0.0f);
            acc[3] += fmaf(fvB1, bB - tB, tB);
        }
        Tc = Tn;
    }

    const float a = prelu[0];
    #pragma unroll
    for (int j = 0; j < 4; ++j) {
        const float v = acc[j];
        out[((z0 + j) << 14) + (y << 7) + x] = (v >= 0.0f) ? v : a * v;
    }
}

// ---------------------------------------------------------------------------
extern "C" void kernel_launch(void* const* d_in, const int* in_sizes, int n_in,
                              void* d_out, int out_size, void* d_ws, size_t ws_size,
                              hipStream_t stream) {
    const float* sino  = (const float*)d_in[0];   // (1,1,96,96,192)
    const float* wgt   = (const float*)d_in[1];   // (1,96,96,192)
    const float* prelu = (const float*)d_in[2];   // (1,)
    float* out = (float*)d_out;                   // 128^3 floats

    unsigned char* wsb = (unsigned char*)d_ws;
    unsigned* wq_dw  = (unsigned*)wsb;                                   // 18.87 MB quads (rows 16..111)
    uint2*    tbl    = (uint2*)(wsb + (size_t)NPROJ * WQSLICEB);         // 12.58 MB table
    unsigned* derivp = (unsigned*)(wsb + (size_t)NPROJ * WQSLICEB
                                       + (size_t)NPROJ * NPIX * 8);      // 7.08 MB pairs

    k_deriv <<<dim3(NPROJ * NANG), dim3(192), 0, stream>>>(sino, wgt, derivp);
    k_bp2d_l<<<dim3(NPROJ, 16),    dim3(256), 0, stream>>>(derivp, wq_dw, tbl);
    k_bp3d_t<<<dim3(64, 32),       dim3(256), 0, stream>>>((const unsigned char*)wq_dw, tbl, prelu, out);
}

// Round 8
// 180.517 us; speedup vs baseline: 1.0861x; 1.0861x over previous
//
#include <hip/hip_runtime.h>
#include <hip/hip_fp16.h>
#include <math.h>

#define NPROJ 96
#define NANG  96
#define DET   192
#define NPIX  16384            // 128*128
#define SLICE (NANG*DET)       // 18432

// wq stores quad rows [16,112) only (reads touch rows 19..111)
#define WQROW0   16
#define WQROWS   96
#define WQSLICEB (WQROWS*128*16)   // 196608 bytes per projection

// DSD/DU = DSD/DV = 1000/3.5
#define KPROJ 285.7142857142857f

__device__ __forceinline__ float frcp(float x) { return __builtin_amdgcn_rcpf(x); }

__device__ __forceinline__ float ffract(float x) {
#if __has_builtin(__builtin_amdgcn_fractf)
    return __builtin_amdgcn_fractf(x);
#else
    return x - floorf(x);
#endif
}

typedef __fp16 h2 __attribute__((ext_vector_type(2)));

__device__ __forceinline__ unsigned pack2(float a, float b) {
    h2 p = __builtin_amdgcn_cvt_pkrtz(a, b);
    return __builtin_bit_cast(unsigned, p);
}
__device__ __forceinline__ h2 as_h2(unsigned u) { return __builtin_bit_cast(h2, u); }

#if __has_builtin(__builtin_amdgcn_fdot2)
#define FDOT2(a, b, c) __builtin_amdgcn_fdot2((a), (b), (c), false)
#else
__device__ __forceinline__ float FDOT2(h2 a, h2 b, float c) {
    return c + (float)a[0] * (float)b[0] + (float)a[1] * (float)b[1];
}
#endif

// ---------------------------------------------------------------------------
// K1: deriv = grad_lastdim(sino * weight) -> DIFFERENCE pairs:
// derivp[row][d] = half2(g[d], g[d+1]-g[d])  =>  lerp weight is (1, f).
// ---------------------------------------------------------------------------
__global__ __launch_bounds__(192) void k_deriv(const float* __restrict__ sino,
                                               const float* __restrict__ wgt,
                                               unsigned* __restrict__ derivp) {
    __shared__ float row[DET];
    const int r = blockIdx.x;          // p*96 + a
    const int d = threadIdx.x;         // 0..191
    const int base = r * DET + d;
    row[d] = sino[base] * wgt[base];
    __syncthreads();
    auto grad = [&](int i) -> float {
        i = (i > DET-1) ? DET-1 : i;
        if (i == 0)       return row[1] - row[0];
        if (i == DET-1)   return row[DET-1] - row[DET-2];
        return 0.5f * (row[i+1] - row[i-1]);
    };
    const float g0 = grad(d), g1 = grad(d+1);
    derivp[base] = pack2(g0, g1 - g0);
}

// ---------------------------------------------------------------------------
// K2: 2D backprojection + cosine weighting — r6 version VERBATIM (r7's
// LDS-staged variant was +12 us: barrier-per-angle + divergence outweighed
// the gather-replay saving; global gathers with lane-adjacent pixels span
// only ~3-4 cachelines per wave-load).
// Epilogue emits the K3 per-(beta,pixel) prologue table:
//   tbl[p][pix] = { wuw = pack2(w2, fu*w2),  kzi = bits(Kz)&~127 | iu0 }
// (iu0 in Kz's low 7 mantissa bits: <=8e-6 rel perturbation, ~3e-4 px in pv)
// Quad layout trimmed to rows [16,112). grid (96 p, 32 chunks), block 256.
// ---------------------------------------------------------------------------
__global__ __launch_bounds__(256) void k_bp2d(const unsigned* __restrict__ derivp,
                                              unsigned* __restrict__ wq_dw,
                                              uint2* __restrict__ tbl) {
    __shared__ float sc[NANG], ss[NANG];
    __shared__ float buf[512];
    const int p   = blockIdx.x;
    const int tid = threadIdx.x;

    if (tid < NANG) {
        float s_, c_;
        sincosf((float)tid * (float)(3.14159265358979323846 / 96.0), &s_, &c_);
        sc[tid] = c_; ss[tid] = s_;
    }

    // K3 cone-beam geometry trig for this projection (uniform over block)
    float sb2, cb2;
    sincosf((float)p * (float)(2.0 * 3.14159265358979323846 / 96.0), &sb2, &cb2);

    const int pixbase = blockIdx.y * 512;
    float acc[2], fx[2], fy[2];
    #pragma unroll
    for (int i = 0; i < 2; ++i) {
        const int pix = pixbase + i*256 + tid;
        fx[i] = (float)(pix & 127) - 63.5f;
        fy[i] = (float)(pix >> 7)  - 63.5f;
        acc[i] = 0.0f;
    }
    __syncthreads();   // trig ready

    const unsigned* rowp = derivp + p * SLICE;   // advances by DET per angle
    for (int a = 0; a < NANG; ++a, rowp += DET) {
        const float cb = sc[a], sb = ss[a];
        #pragma unroll
        for (int i = 0; i < 2; ++i) {
            const float pos = fmaf(cb, fx[i], fmaf(sb, fy[i], 95.5f));
            const int   i0  = (int)pos;            // pos > 0 always
            const float f   = ffract(pos);
            acc[i] = FDOT2(as_h2(rowp[i0]), as_h2(pack2(1.0f, f)), acc[i]);
        }
    }

    #pragma unroll
    for (int i = 0; i < 2; ++i) {
        const float w = 1000.0f * rsqrtf(1000000.0f + fx[i]*fx[i] + fy[i]*fy[i]);
        buf[i*256 + tid] = acc[i] * w;
    }
    __syncthreads();

    unsigned* sq = wq_dw + p * (WQROWS * 128 * 4);
    uint2*    tp = tbl   + p * NPIX;
    #pragma unroll
    for (int i = 0; i < 2; ++i) {
        const int l   = i*256 + tid;
        const int pix = pixbase + l;
        const int u   = pix & 127;
        const int v   = pix >> 7;
        const float v0 = buf[l];
        const float v1 = (u < 127) ? buf[l + 1] : 0.0f;   // u=127 pair unused
        const unsigned pr = pack2(v0, v1 - v0);
        #pragma unroll
        for (int k = 0; k < 4; ++k) {
            const int vb = v - k;
            if (vb >= WQROW0 && vb < WQROW0 + WQROWS)
                sq[(((vb - WQROW0) << 7) + u) << 2 | k] = pr;
        }
        // K3 prologue table entry for (p, pix)
        const float t3   = fmaf(fx[i], cb2,  fy[i] * sb2);
        const float sd3  = fmaf(fy[i], cb2, -fx[i] * sb2);
        const float invr = frcp(500.0f + t3);
        const float pu   = fmaf(KPROJ * sd3, invr, 63.5f);
        const int   iu0  = (int)pu;              // [11,116]
        const float fu   = ffract(pu);
        float w2 = 1000.0f * invr; w2 *= w2;
        const float Kz   = KPROJ * invr;         // > 0
        const unsigned kzi = (__builtin_bit_cast(unsigned, Kz) & ~127u) | (unsigned)iu0;
        uint2 e; e.x = pack2(w2, fu * w2); e.y = kzi;
        tp[pix] = e;                             // coalesced dwordx2
    }
}

// ---------------------------------------------------------------------------
// K3: 3D cone-beam backprojection + PReLU — r6 math, two changes:
//  (1) 32-bit SADDR addressing: scalar base pointers + unsigned byte
//      offsets (all buffers < 4 GB) replace per-lane 64-bit pointer walks
//      and v_add_co/v_addc pairs per gather (~10 slots/beta).
//  (2) r5-shape pipeline: table prefetched TWO betas ahead, quad gathers
//      issued ONE beta ahead (ISSUE(b+1) before MATH(b), named QS structs,
//      static indexing). Load->use distance is structural (issued in the
//      previous unroll half). No tbl overrun: max index read is 95.
// Numerics bit-identical to r6. grid (64 y-pairs, 32 z-chunks) = 2048
// blocks = 32 waves/CU. No LDS, no barriers, no trig. pu in [11,116],
// pv in [19,108] -> no masks.
// ---------------------------------------------------------------------------
struct QS {
    uint4    q0, q1;           // quad rows ivA..ivA+3 for z-pairs 0,1
    unsigned wuw;              // (w2, fu*w2) packed fp16
    float    fvA0, fvB0, fvA1, fvB1;
    int      d0, d1;           // ivB - ivA (0 or 1)
};

__global__ __launch_bounds__(256, 8) void k_bp3d_t2(const unsigned char* __restrict__ wq,
                                                    const unsigned char* __restrict__ tbl8,
                                                    const float* __restrict__ prelu,
                                                    float* __restrict__ out) {
    const int tid = threadIdx.x;
    const int x   = tid & 127;
    const int y   = (blockIdx.x << 1) | (tid >> 7);
    const int z0  = blockIdx.y << 2;
    const int pix = (y << 7) + x;

    const float zlo = (float)z0 - 63.5f;

    float acc[4];
    #pragma unroll
    for (int j = 0; j < 4; ++j) acc[j] = 0.0f;

    const unsigned pixoff = ((unsigned)pix) << 3;      // tbl byte offset

    auto TLOAD = [&](int b) -> uint2 {
        return *(const uint2*)(tbl8 + (pixoff + (unsigned)b * (NPIX * 8u)));
    };

    auto ISSUE = [&](QS& S, uint2 T, int b) {
        S.wuw = T.x;
        const int   iu0 = (int)(T.y & 127u);
        const float Kz  = __builtin_bit_cast(float, T.y & ~127u);
        // 32-bit byte offset base: slice + column - row-trim (wraps ok, final >= 0)
        const unsigned sbase = (unsigned)b * (unsigned)WQSLICEB
                             + (unsigned)(iu0 << 4) - (unsigned)(WQROW0 << 11);

        const float pvA0 = fmaf(Kz, zlo, 63.5f);
        const float pvB0 = pvA0 + Kz;
        const int   ivA0 = (int)pvA0;            // [19,108]
        S.d0   = (int)pvB0 - ivA0;               // 0 or 1
        S.fvA0 = ffract(pvA0);
        S.fvB0 = ffract(pvB0);
        S.q0   = *(const uint4*)(wq + (sbase + ((unsigned)ivA0 << 11)));

        const float pvA1 = fmaf(Kz, zlo + 2.0f, 63.5f);
        const float pvB1 = pvA1 + Kz;
        const int   ivA1 = (int)pvA1;
        S.d1   = (int)pvB1 - ivA1;
        S.fvA1 = ffract(pvA1);
        S.fvB1 = ffract(pvB1);
        S.q1   = *(const uint4*)(wq + (sbase + ((unsigned)ivA1 << 11)));
    };

    auto MATH = [&](const QS& S) {
        const h2 wuw = as_h2(S.wuw);
        {
            const float tA = FDOT2(as_h2(S.q0.x), wuw, 0.0f);
            const float bA = FDOT2(as_h2(S.q0.y), wuw, 0.0f);
            acc[0] += fmaf(S.fvA0, bA - tA, tA);
            const unsigned tBv = S.d0 ? S.q0.y : S.q0.x;
            const unsigned bBv = S.d0 ? S.q0.z : S.q0.y;
            const float tB = FDOT2(as_h2(tBv), wuw, 0.0f);
            const float bB = FDOT2(as_h2(bBv), wuw, 0.0f);
            acc[1] += fmaf(S.fvB0, bB - tB, tB);
        }
        {
            const float tA = FDOT2(as_h2(S.q1.x), wuw, 0.0f);
            const float bA = FDOT2(as_h2(S.q1.y), wuw, 0.0f);
            acc[2] += fmaf(S.fvA1, bA - tA, tA);
            const unsigned tBv = S.d1 ? S.q1.y : S.q1.x;
            const unsigned bBv = S.d1 ? S.q1.z : S.q1.y;
            const float tB = FDOT2(as_h2(tBv), wuw, 0.0f);
            const float bB = FDOT2(as_h2(bBv), wuw, 0.0f);
            acc[3] += fmaf(S.fvB1, bB - tB, tB);
        }
    };

    QS qa, qb;
    uint2 Ta = TLOAD(0);
    uint2 Tb = TLOAD(1);
    ISSUE(qa, Ta, 0);
    for (int b = 0; b < 94; b += 2) {
        Ta = TLOAD(b + 2);          // 2-ahead table prefetch
        ISSUE(qb, Tb, b + 1);       // 1-ahead quad issue
        MATH(qa);                   // consume quads issued last half-iter
        Tb = TLOAD(b + 3);          // max index 95 — no overrun
        ISSUE(qa, Ta, b + 2);
        MATH(qb);
    }
    ISSUE(qb, Tb, 95);
    MATH(qa);                       // beta 94
    MATH(qb);                       // beta 95

    const float a = prelu[0];
    #pragma unroll
    for (int j = 0; j < 4; ++j) {
        const float v = acc[j];
        out[((z0 + j) << 14) + (y << 7) + x] = (v >= 0.0f) ? v : a * v;
    }
}

// ---------------------------------------------------------------------------
extern "C" void kernel_launch(void* const* d_in, const int* in_sizes, int n_in,
                              void* d_out, int out_size, void* d_ws, size_t ws_size,
                              hipStream_t stream) {
    const float* sino  = (const float*)d_in[0];   // (1,1,96,96,192)
    const float* wgt   = (const float*)d_in[1];   // (1,96,96,192)
    const float* prelu = (const float*)d_in[2];   // (1,)
    float* out = (float*)d_out;                   // 128^3 floats

    unsigned char* wsb = (unsigned char*)d_ws;
    unsigned* wq_dw  = (unsigned*)wsb;                                   // 18.87 MB quads (rows 16..111)
    uint2*    tbl    = (uint2*)(wsb + (size_t)NPROJ * WQSLICEB);         // 12.58 MB table
    unsigned* derivp = (unsigned*)(wsb + (size_t)NPROJ * WQSLICEB
                                       + (size_t)NPROJ * NPIX * 8);      // 7.08 MB pairs

    k_deriv  <<<dim3(NPROJ * NANG), dim3(192), 0, stream>>>(sino, wgt, derivp);
    k_bp2d   <<<dim3(NPROJ, 32),    dim3(256), 0, stream>>>(derivp, wq_dw, tbl);
    k_bp3d_t2<<<dim3(64, 32),       dim3(256), 0, stream>>>((const unsigned char*)wq_dw,
                                                            (const unsigned char*)tbl, prelu, out);
}